// Round 2
// baseline (2283.448 us; speedup 1.0000x reference)
//
#include <hip/hip_runtime.h>

#define BATCH 8
#define CHN 256
#define HH 64
#define WW 64
#define HW (HH*WW)
#define DGRP 4
#define CG 64
#define KK 9
#define NGK 36
#define GN 32
#define CPG 8
#define EPSV 1e-5f

// Transpose w_deform (o, g*64+c, k) -> w_t[((g*9+k)*64+c)*256 + o]
__global__ __launch_bounds__(256) void wt_kernel(const float* __restrict__ wd,
                                                 float* __restrict__ wt) {
  int idx = blockIdx.x * 256 + threadIdx.x;     // 36*64*256 = 589824 total
  int o  = idx & 255;
  int c  = (idx >> 8) & 63;
  int gk = idx >> 14;                           // 0..35
  int g = gk / 9, k = gk - g * 9;
  wt[idx] = wd[(o * 256 + g * 64 + c) * 9 + k];
}

__global__ __launch_bounds__(256) void conv_kernel(
    const float* __restrict__ x, const float* __restrict__ shp,
    const float* __restrict__ woff, const float* __restrict__ wt,
    float* __restrict__ out) {
  __shared__ float  s_woff[288];
  __shared__ float  s_sh[4][16];
  __shared__ float2 s_off[NGK][16];
  __shared__ float  s_smp[64][16];

  const int b  = blockIdx.x >> 8;
  const int p0 = (blockIdx.x & 255) << 4;       // 16-px tile, never crosses a row
  const int t  = threadIdx.x;
  const int tx = t & 15, ty = t >> 4;

  for (int i = t; i < 288; i += 256) s_woff[i] = woff[i];   // FIXED: was if(t<288) with 256 threads
  if (t < 64) {
    int cc = t >> 4, px = t & 15;
    s_sh[cc][px] = shp[(b * 4 + cc) * HW + p0 + px];
  }
  __syncthreads();
  // offsets: o-channel = gk*2 + {0:dy, 1:dx}
  for (int i = t; i < NGK * 16; i += 256) {
    int px = i & 15;
    int gk = i >> 4;
    float a0 = s_sh[0][px], a1 = s_sh[1][px], a2 = s_sh[2][px], a3 = s_sh[3][px];
    const float* wy = &s_woff[gk * 8];
    float dy = wy[0]*a0 + wy[1]*a1 + wy[2]*a2 + wy[3]*a3;
    float dx = wy[4]*a0 + wy[5]*a1 + wy[6]*a2 + wy[7]*a3;
    s_off[gk][px] = make_float2(dy, dx);
  }

  float acc[16];
#pragma unroll
  for (int i = 0; i < 16; ++i) acc[i] = 0.f;

  const float fh = (float)(p0 >> 6);
  const float fw = (float)((p0 & 63) + tx);

  for (int g = 0; g < DGRP; ++g) {
    const float* __restrict__ xg = x + (size_t)((b * DGRP + g) * CG) * HW;
    for (int k = 0; k < KK; ++k) {
      const int gk = g * 9 + k;
      __syncthreads();   // covers s_off fill (iter 0) and s_smp reuse (iters >0)
      float2 od = s_off[gk][tx];
      float py  = od.x + fh + (float)(k / 3 - 1);
      float pxp = od.y + fw + (float)(k % 3 - 1);
      float y0f = floorf(py), x0f = floorf(pxp);
      float ly = py - y0f, lx = pxp - x0f;
      int y0 = (int)y0f, x0 = (int)x0f;
      float m_y0 = (y0 >=  0 && y0 <= 63) ? 1.f : 0.f;
      float m_y1 = (y0 >= -1 && y0 <= 62) ? 1.f : 0.f;
      float m_x0 = (x0 >=  0 && x0 <= 63) ? 1.f : 0.f;
      float m_x1 = (x0 >= -1 && x0 <= 62) ? 1.f : 0.f;
      float w00 = (1.f - ly) * (1.f - lx) * m_y0 * m_x0;
      float w01 = (1.f - ly) * lx         * m_y0 * m_x1;
      float w10 = ly         * (1.f - lx) * m_y1 * m_x0;
      float w11 = ly         * lx         * m_y1 * m_x1;
      int yc0 = min(max(y0, 0), 63),     yc1 = min(max(y0 + 1, 0), 63);
      int xc0 = min(max(x0, 0), 63),     xc1 = min(max(x0 + 1, 0), 63);
      int i00 = (yc0 << 6) + xc0, i01 = (yc0 << 6) + xc1;
      int i10 = (yc1 << 6) + xc0, i11 = (yc1 << 6) + xc1;
#pragma unroll
      for (int j = 0; j < 4; ++j) {
        const float* xc = xg + (ty + (j << 4)) * HW;
        float v = xc[i00]*w00 + xc[i01]*w01 + xc[i10]*w10 + xc[i11]*w11;
        s_smp[ty + (j << 4)][tx] = v;
      }
      __syncthreads();
      const float* wp = wt + (size_t)(gk * CG) * CHN + ty * 16;
      for (int c = 0; c < CG; ++c) {
        float s = s_smp[c][tx];
        const float4* q4 = (const float4*)(wp + c * CHN);
        float4 q0 = q4[0], q1 = q4[1], q2 = q4[2], q3 = q4[3];
        acc[0]  = fmaf(s, q0.x, acc[0]);
        acc[1]  = fmaf(s, q0.y, acc[1]);
        acc[2]  = fmaf(s, q0.z, acc[2]);
        acc[3]  = fmaf(s, q0.w, acc[3]);
        acc[4]  = fmaf(s, q1.x, acc[4]);
        acc[5]  = fmaf(s, q1.y, acc[5]);
        acc[6]  = fmaf(s, q1.z, acc[6]);
        acc[7]  = fmaf(s, q1.w, acc[7]);
        acc[8]  = fmaf(s, q2.x, acc[8]);
        acc[9]  = fmaf(s, q2.y, acc[9]);
        acc[10] = fmaf(s, q2.z, acc[10]);
        acc[11] = fmaf(s, q2.w, acc[11]);
        acc[12] = fmaf(s, q3.x, acc[12]);
        acc[13] = fmaf(s, q3.y, acc[13]);
        acc[14] = fmaf(s, q3.z, acc[14]);
        acc[15] = fmaf(s, q3.w, acc[15]);
      }
    }
  }
  float* op = out + (size_t)(b * CHN + ty * 16) * HW + p0 + tx;
#pragma unroll
  for (int i = 0; i < 16; ++i) op[i * HW] = acc[i];
}

// Per (b, gn_group) mean / rsqrt(var+eps); group = 8 contiguous channels.
__global__ __launch_bounds__(256) void stats_kernel(const float* __restrict__ o,
                                                    float2* __restrict__ st) {
  const int bg = blockIdx.x;                       // b*32 + gg
  const float4* base = (const float4*)(o + (size_t)bg * CPG * HW);
  float s = 0.f, s2 = 0.f;
  for (int i = threadIdx.x; i < CPG * HW / 4; i += 256) {
    float4 v = base[i];
    s  += v.x + v.y + v.z + v.w;
    s2 += v.x*v.x + v.y*v.y + v.z*v.z + v.w*v.w;
  }
  __shared__ float rs[256], rs2[256];
  rs[threadIdx.x] = s; rs2[threadIdx.x] = s2;
  __syncthreads();
  for (int d = 128; d > 0; d >>= 1) {
    if (threadIdx.x < d) {
      rs[threadIdx.x]  += rs[threadIdx.x + d];
      rs2[threadIdx.x] += rs2[threadIdx.x + d];
    }
    __syncthreads();
  }
  if (threadIdx.x == 0) {
    const float inv = 1.f / (CPG * HW);
    float mu  = rs[0] * inv;
    float var = rs2[0] * inv - mu * mu;
    st[bg] = make_float2(mu, rsqrtf(var + EPSV));
  }
}

__global__ __launch_bounds__(256) void norm_kernel(float* __restrict__ o,
    const float2* __restrict__ st, const float* __restrict__ gamma,
    const float* __restrict__ beta) {
  int idx = blockIdx.x * 256 + threadIdx.x;       // over float4s: 2097152 total
  float4* p = (float4*)o;
  int c = (idx >> 10) & 255;
  int b = idx >> 18;
  float2 ms = st[b * 32 + (c >> 3)];
  float ga = gamma[c] * ms.y;
  float be = beta[c] - ms.x * ga;
  float4 v = p[idx];
  v.x = fmaxf(fmaf(v.x, ga, be), 0.f);
  v.y = fmaxf(fmaf(v.y, ga, be), 0.f);
  v.z = fmaxf(fmaf(v.z, ga, be), 0.f);
  v.w = fmaxf(fmaf(v.w, ga, be), 0.f);
  p[idx] = v;
}

extern "C" void kernel_launch(void* const* d_in, const int* in_sizes, int n_in,
                              void* d_out, int out_size, void* d_ws, size_t ws_size,
                              hipStream_t stream) {
  const float* x     = (const float*)d_in[0];
  const float* shp   = (const float*)d_in[1];
  const float* woff  = (const float*)d_in[2];
  const float* wdef  = (const float*)d_in[3];
  const float* gamma = (const float*)d_in[4];
  const float* beta  = (const float*)d_in[5];
  float*  out = (float*)d_out;
  float*  wtp = (float*)d_ws;                              // 589824 floats
  float2* st  = (float2*)((char*)d_ws + 589824 * sizeof(float)); // 256 float2

  hipLaunchKernelGGL(wt_kernel,    dim3(2304), dim3(256), 0, stream, wdef, wtp);
  hipLaunchKernelGGL(conv_kernel,  dim3(2048), dim3(256), 0, stream, x, shp, woff, wtp, out);
  hipLaunchKernelGGL(stats_kernel, dim3(256),  dim3(256), 0, stream, out, st);
  hipLaunchKernelGGL(norm_kernel,  dim3(8192), dim3(256), 0, stream, out, st, gamma, beta);
}

// Round 3
// 353.993 us; speedup vs baseline: 6.4506x; 6.4506x over previous
//
#include <hip/hip_runtime.h>
#include <hip/hip_bf16.h>

#define BATCH 8
#define CHN 256
#define HH 64
#define WW 64
#define HW (HH*WW)
#define DGRP 4
#define CG 64
#define KK 9
#define NGK 36
#define CPG 8
#define EPSV 1e-5f

typedef __attribute__((ext_vector_type(8))) short short8;
typedef __attribute__((ext_vector_type(4))) float f32x4;

// w_deform (o, g*64+c, kk) fp32 -> w2 bf16 [gk][o][c]:  w2[((gk*256)+o)*64 + c]
__global__ __launch_bounds__(256) void wt2_kernel(const float* __restrict__ wd,
                                                  __hip_bfloat16* __restrict__ w2) {
  int idx = blockIdx.x * 256 + threadIdx.x;     // 36*256*64 = 589824
  int c  = idx & 63;
  int o  = (idx >> 6) & 255;
  int gk = idx >> 14;                           // 0..35
  int g = gk / 9, k = gk - g * 9;
  w2[idx] = __float2bfloat16(wd[(o * 256 + g * 64 + c) * 9 + k]);
}

// One block per (b, image row h). 4 waves; wave wv computes o in [wv*64, wv*64+64)
// for the 64 pixels of row h, over K = 36 taps x 64 channels via bf16 MFMA.
__global__ __launch_bounds__(256) void conv_kernel(
    const float* __restrict__ x, const float* __restrict__ shp,
    const float* __restrict__ woff, const __hip_bfloat16* __restrict__ w2,
    float* __restrict__ out) {
  __shared__ float s_woff[288];
  __shared__ __align__(16) unsigned short s_S[64 * 72];   // S[px][c], stride 72 bf16

  const int b = blockIdx.x >> 6;
  const int h = blockIdx.x & 63;
  const int t = threadIdx.x;
  const int wv = t >> 6;            // wave id: o-quadrant
  const int lane = t & 63;
  const int quad = lane >> 4;
  const int l15 = lane & 15;
  const int px = t & 63;            // pixel (column) this thread samples
  const int cphase = t >> 6;        // 16-channel slice this thread samples

  for (int i = t; i < 288; i += 256) s_woff[i] = woff[i];

  // per-thread shape row values (redundant x4 across cphase; trivial)
  const float a0 = shp[((b * 4 + 0) * HH + h) * WW + px];
  const float a1 = shp[((b * 4 + 1) * HH + h) * WW + px];
  const float a2 = shp[((b * 4 + 2) * HH + h) * WW + px];
  const float a3 = shp[((b * 4 + 3) * HH + h) * WW + px];

  f32x4 acc[4][4];
#pragma unroll
  for (int mo = 0; mo < 4; ++mo)
#pragma unroll
    for (int np = 0; np < 4; ++np) acc[mo][np] = (f32x4){0.f, 0.f, 0.f, 0.f};

  __syncthreads();   // s_woff ready

  const unsigned short* w2u = (const unsigned short*)w2;

  for (int gk = 0; gk < NGK; ++gk) {
    const int g = gk / 9, k = gk - g * 9;

    // ---- per-thread sample descriptor (offsets shared across the 64 c of group g)
    const float* wy = &s_woff[gk * 8];
    float dy = wy[0] * a0 + wy[1] * a1 + wy[2] * a2 + wy[3] * a3;
    float dx = wy[4] * a0 + wy[5] * a1 + wy[6] * a2 + wy[7] * a3;
    float py  = dy + (float)(h + k / 3 - 1);
    float pxp = dx + (float)(px + k % 3 - 1);
    float y0f = floorf(py), x0f = floorf(pxp);
    float ly = py - y0f, lx = pxp - x0f;
    int y0 = (int)y0f, x0 = (int)x0f;
    float m_y0 = (y0 >=  0 && y0 <= 63) ? 1.f : 0.f;
    float m_y1 = (y0 >= -1 && y0 <= 62) ? 1.f : 0.f;
    float m_x0 = (x0 >=  0 && x0 <= 63) ? 1.f : 0.f;
    float m_x1 = (x0 >= -1 && x0 <= 62) ? 1.f : 0.f;
    float w00 = (1.f - ly) * (1.f - lx) * m_y0 * m_x0;
    float w01 = (1.f - ly) * lx         * m_y0 * m_x1;
    float w10 = ly         * (1.f - lx) * m_y1 * m_x0;
    float w11 = ly         * lx         * m_y1 * m_x1;
    int yc0 = min(max(y0, 0), 63),     yc1 = min(max(y0 + 1, 0), 63);
    int xc0 = min(max(x0, 0), 63),     xc1 = min(max(x0 + 1, 0), 63);
    int i00 = (yc0 << 6) + xc0, i01 = (yc0 << 6) + xc1;
    int i10 = (yc1 << 6) + xc0, i11 = (yc1 << 6) + xc1;

    __syncthreads();   // previous iter's MFMA reads of s_S complete

    // ---- sample 16 channels (2 at a time, packed bf16x2 write)
    const float* xg = x + (((size_t)(b * DGRP + g) * CG) << 12);
#pragma unroll
    for (int i = 0; i < 8; ++i) {
      const int c0 = (cphase << 4) + (i << 1);
      const float* xa = xg + ((size_t)c0 << 12);
      const float* xb = xa + HW;
      float v0 = xa[i00] * w00 + xa[i01] * w01 + xa[i10] * w10 + xa[i11] * w11;
      float v1 = xb[i00] * w00 + xb[i01] * w01 + xb[i10] * w10 + xb[i11] * w11;
      __hip_bfloat162 pk = __float22bfloat162_rn(make_float2(v0, v1));
      *(unsigned int*)&s_S[px * 72 + c0] = *(unsigned int*)&pk;
    }
    __syncthreads();   // s_S ready

    // ---- MFMA: A = W[gk] (256o x 64c, bf16, o-major), B = S (64c x 64px)
    short8 af[4][2];
#pragma unroll
    for (int mo = 0; mo < 4; ++mo)
#pragma unroll
      for (int ks = 0; ks < 2; ++ks)
        af[mo][ks] = *(const short8*)(w2u +
            (((gk << 8) + (wv << 6) + (mo << 4) + l15) << 6) + (ks << 5) + (quad << 3));
#pragma unroll
    for (int np = 0; np < 4; ++np) {
#pragma unroll
      for (int ks = 0; ks < 2; ++ks) {
        short8 bf = *(const short8*)(s_S + (np * 16 + l15) * 72 + (ks << 5) + (quad << 3));
#pragma unroll
        for (int mo = 0; mo < 4; ++mo)
          acc[mo][np] = __builtin_amdgcn_mfma_f32_16x16x32_bf16(af[mo][ks], bf, acc[mo][np], 0, 0, 0);
      }
    }
  }

  // ---- epilogue: D lane layout col(px)=l15, row(o)=quad*4+r
  float* ob = out + (((size_t)b << 8) << 12) + h * WW;
#pragma unroll
  for (int mo = 0; mo < 4; ++mo)
#pragma unroll
    for (int np = 0; np < 4; ++np)
#pragma unroll
      for (int r = 0; r < 4; ++r)
        ob[((size_t)((wv << 6) + (mo << 4) + (quad << 2) + r) << 12) + (np << 4) + l15] =
            acc[mo][np][r];
}

// Per (b, gn_group) mean / rsqrt(var+eps); group = 8 contiguous channels.
__global__ __launch_bounds__(256) void stats_kernel(const float* __restrict__ o,
                                                    float2* __restrict__ st) {
  const int bg = blockIdx.x;                       // b*32 + gg
  const float4* base = (const float4*)(o + (size_t)bg * CPG * HW);
  float s = 0.f, s2 = 0.f;
  for (int i = threadIdx.x; i < CPG * HW / 4; i += 256) {
    float4 v = base[i];
    s  += v.x + v.y + v.z + v.w;
    s2 += v.x*v.x + v.y*v.y + v.z*v.z + v.w*v.w;
  }
  __shared__ float rs[256], rs2[256];
  rs[threadIdx.x] = s; rs2[threadIdx.x] = s2;
  __syncthreads();
  for (int d = 128; d > 0; d >>= 1) {
    if (threadIdx.x < d) {
      rs[threadIdx.x]  += rs[threadIdx.x + d];
      rs2[threadIdx.x] += rs2[threadIdx.x + d];
    }
    __syncthreads();
  }
  if (threadIdx.x == 0) {
    const float inv = 1.f / (CPG * HW);
    float mu  = rs[0] * inv;
    float var = rs2[0] * inv - mu * mu;
    st[bg] = make_float2(mu, rsqrtf(var + EPSV));
  }
}

__global__ __launch_bounds__(256) void norm_kernel(float* __restrict__ o,
    const float2* __restrict__ st, const float* __restrict__ gamma,
    const float* __restrict__ beta) {
  int idx = blockIdx.x * 256 + threadIdx.x;       // over float4s: 2097152 total
  float4* p = (float4*)o;
  int c = (idx >> 10) & 255;
  int b = idx >> 18;
  float2 ms = st[b * 32 + (c >> 3)];
  float ga = gamma[c] * ms.y;
  float be = beta[c] - ms.x * ga;
  float4 v = p[idx];
  v.x = fmaxf(fmaf(v.x, ga, be), 0.f);
  v.y = fmaxf(fmaf(v.y, ga, be), 0.f);
  v.z = fmaxf(fmaf(v.z, ga, be), 0.f);
  v.w = fmaxf(fmaf(v.w, ga, be), 0.f);
  p[idx] = v;
}

extern "C" void kernel_launch(void* const* d_in, const int* in_sizes, int n_in,
                              void* d_out, int out_size, void* d_ws, size_t ws_size,
                              hipStream_t stream) {
  const float* x     = (const float*)d_in[0];
  const float* shp   = (const float*)d_in[1];
  const float* woff  = (const float*)d_in[2];
  const float* wdef  = (const float*)d_in[3];
  const float* gamma = (const float*)d_in[4];
  const float* beta  = (const float*)d_in[5];
  float* out = (float*)d_out;
  __hip_bfloat16* w2 = (__hip_bfloat16*)d_ws;                    // 589824 bf16 = 1.18 MB
  float2* st = (float2*)((char*)d_ws + 589824 * sizeof(__hip_bfloat16)); // 256 float2

  hipLaunchKernelGGL(wt2_kernel,   dim3(2304), dim3(256), 0, stream, wdef, w2);
  hipLaunchKernelGGL(conv_kernel,  dim3(512),  dim3(256), 0, stream, x, shp, woff, w2, out);
  hipLaunchKernelGGL(stats_kernel, dim3(256),  dim3(256), 0, stream, out, st);
  hipLaunchKernelGGL(norm_kernel,  dim3(8192), dim3(256), 0, stream, out, st, gamma, beta);
}